// Round 6
// baseline (346.892 us; speedup 1.0000x reference)
//
#include <hip/hip_runtime.h>

// LightshiftaddLayer — R10 (resubmit; previous bench died on container
// acquisition, not kernel): FUSED gemm+conv, lconv kernel deleted.
//  Key change: GEMM m-tiles are (fixed b, contiguous 128 t) instead of
//  (t,b)-interleaved rows. Each block computes Y-tile for t in
//  [chunk*122-3, chunk*122+125), reuses the dead K-loop LDS as a transposed
//  [128 ch][128 t] bf16 tile (XOR-swizzled), and applies the 7-tap conv
//  in-block, storing fp32 straight to out. The 67MB Y write + ~470MB re-read
//  and the entire lconv kernel (~90us, latency-bound) disappear; halo is
//  recomputed (+6% gemm work, 34 chunks of 122 outputs from 128 computed).
//  K-loop itself is the best-measured R7 config: 256 thr, 4 waves 64x64,
//  BK=32 dbuf (32KB), T2 swizzle (0 conflicts), gload_lds for B.
//  Zero-padding: invalid-t rows masked to 0 at the LDS write (bias must not
//  leak into conv padding); X loads row-clamped + zero-selected.
constexpr int T_DIM = 4096;
constexpr int B_DIM = 16;
constexpr int C_DIM = 512;
constexpr int K_CONV = 7;
constexpr int BC = B_DIM * C_DIM;      // 8192
constexpr int BK = 32;
constexpr int NSTEP = C_DIM / BK;      // 16 K-steps
constexpr int TOUT = 122;              // outputs per chunk (128 - 2*3 halo)
constexpr int NCH = 34;                // ceil(4096/122)

typedef __attribute__((ext_vector_type(8))) short bf16x8;
typedef __attribute__((ext_vector_type(4))) float f32x4;
typedef __attribute__((ext_vector_type(8))) float f32x8;
typedef __attribute__((ext_vector_type(4))) unsigned int u32x4;
typedef __attribute__((ext_vector_type(2))) unsigned int u32x2;

__device__ __forceinline__ unsigned short f2bf(float f) {
  unsigned u = __float_as_uint(f);
  u += 0x7fffu + ((u >> 16) & 1u);   // RNE
  return (unsigned short)(u >> 16);
}
__device__ __forceinline__ unsigned pack2(float a, float b) {
  return (unsigned)f2bf(a) | (((unsigned)f2bf(b)) << 16);
}
__device__ __forceinline__ f32x8 unpack8(u32x4 u) {
  f32x8 r;
#pragma unroll
  for (int i = 0; i < 4; ++i) {
    unsigned w = u[i];
    r[2 * i]     = __uint_as_float(w << 16);
    r[2 * i + 1] = __uint_as_float(w & 0xffff0000u);
  }
  return r;
}

// ---------------------------------------------------------------- quantize W -> bf16
__global__ __launch_bounds__(256) void quantize_w(
    const float* __restrict__ W, unsigned short* __restrict__ Wq) {
  int i = blockIdx.x * 256 + threadIdx.x;
  float w = W[i];
  float a = fabsf(w) + 1e-12f;
  float q = exp2f(rintf(log2f(a)));       // rintf = RNE, matches jnp.round
  q = (w > 0.f) ? q : ((w < 0.f) ? -q : 0.f);
  Wq[i] = f2bf(q);                        // powers of two: exact in bf16
}

// ---------------------------------------------------------------- fused GEMM+conv
__global__ __launch_bounds__(256, 4) void gemm_conv(
    const float* __restrict__ X, const short* __restrict__ Bt,
    const float* __restrict__ bias, const float* __restrict__ Wc,
    float* __restrict__ Out) {
  constexpr int K = C_DIM;
  // 32 KB union: K-loop pipeline {As0,As1,Bs0,Bs1} (8 KB each), then
  // after the loop the transposed Y-tile [128 ch][128 t] bf16 (32 KB).
  __shared__ __align__(16) short LdsU[16384];
  short* const As0 = LdsU;
  short* const As1 = LdsU + 4096;
  short* const Bs0 = LdsU + 8192;
  short* const Bs1 = LdsU + 12288;

  // block decode + XCD swizzle: 2176 = 8 * 272 (bijective).
  // Within an XCD, consecutive slots walk np first (4 panels share X rows).
  const int id    = blockIdx.x;
  const int xcd   = id & 7;
  const int slot  = id >> 3;                 // 0..271
  const int np    = slot & 3;
  const int cb    = xcd * 68 + (slot >> 2);  // 0..543
  const int b     = cb & 15;
  const int chunk = cb >> 4;                 // 0..33
  const int n0    = np * 128;
  const int tstart = chunk * TOUT - 3;

  const int t    = threadIdx.x;
  const int lane = t & 63;
  const int wid  = t >> 6;                   // 4 waves: 2x2 of 64x64

  // ---- A staging: thread stages t-rows ar and ar+64 (X row stride = BC),
  // float col (t&3)*8; invalid t rows -> clamped address + zero value.
  const int ar  = t >> 2;                    // 0..63
  const int acq = (t & 3) * 8;
  const int tr0 = tstart + ar;
  const int tr1 = tstart + 64 + ar;
  const bool v0 = (unsigned)tr0 < (unsigned)T_DIM;
  const bool v1 = (unsigned)tr1 < (unsigned)T_DIM;
  const float* pA0 = X + (long)(v0 ? tr0 : 0) * BC + b * C_DIM + acq;
  const float* pA1 = X + (long)(v1 ? tr1 : 0) * BC + b * C_DIM + acq;
  const int awoff = (((t & 3) ^ ((ar >> 1) & 3)) << 4);

  // ---- B staging via global_load_lds (linear dest, pre-swizzled source):
  // logical chunk = (t&3) ^ ((t>>3)&3).
  const int bcs = ((t & 3) ^ ((t >> 3) & 3)) * 8;
  const short* pB = Bt + (long)(n0 + (t >> 2)) * K + bcs;

  // ---- fragment geometry (A frag: A[m=lane&15][k=(lane>>4)*8+j])
  const int fr = lane & 15;
  const int fq = lane >> 4;
  const int wm = (wid >> 1) * 64;
  const int wn = (wid & 1) * 64;
  const int sw = ((fq ^ ((fr >> 1) & 3)) << 4);

  float bv[4];
#pragma unroll
  for (int j = 0; j < 4; ++j) bv[j] = bias[n0 + wn + j * 16 + fr];

  f32x4 ax[4];
  f32x4 acc[4][4] = {};
  const f32x4 zf = {0.f, 0.f, 0.f, 0.f};

  auto loadA = [&](int k0) {
    ax[0] = v0 ? *(const f32x4*)(pA0 + k0)     : zf;
    ax[1] = v0 ? *(const f32x4*)(pA0 + k0 + 4) : zf;
    ax[2] = v1 ? *(const f32x4*)(pA1 + k0)     : zf;
    ax[3] = v1 ? *(const f32x4*)(pA1 + k0 + 4) : zf;
  };
  auto stageB = [&](short* bs, int k0) {
#pragma unroll
    for (int i = 0; i < 2; ++i)
      __builtin_amdgcn_global_load_lds(
          (const __attribute__((address_space(1))) void*)(pB + (long)i * 64 * K + k0),
          (__attribute__((address_space(3))) void*)&bs[i * 2048 + wid * 512],
          16, 0, 0);
  };
  auto writeA = [&](short* as) {
    char* base = (char*)as;
    u32x4 w0, w1;
    w0[0] = pack2(ax[0][0], ax[0][1]);
    w0[1] = pack2(ax[0][2], ax[0][3]);
    w0[2] = pack2(ax[1][0], ax[1][1]);
    w0[3] = pack2(ax[1][2], ax[1][3]);
    w1[0] = pack2(ax[2][0], ax[2][1]);
    w1[1] = pack2(ax[2][2], ax[2][3]);
    w1[2] = pack2(ax[3][0], ax[3][1]);
    w1[3] = pack2(ax[3][2], ax[3][3]);
    *(u32x4*)(base + ar * 64 + awoff)        = w0;
    *(u32x4*)(base + (64 + ar) * 64 + awoff) = w1;
  };
  auto compute = [&](const short* as, const short* bs) {
    const char* ab = (const char*)as;
    const char* bb = (const char*)bs;
    bf16x8 af[4], bfr[4];
#pragma unroll
    for (int i = 0; i < 4; ++i)
      af[i] = *(const bf16x8*)(ab + (wm + i * 16 + fr) * 64 + sw);
#pragma unroll
    for (int j = 0; j < 4; ++j)
      bfr[j] = *(const bf16x8*)(bb + (wn + j * 16 + fr) * 64 + sw);
#pragma unroll
    for (int i = 0; i < 4; ++i)
#pragma unroll
      for (int j = 0; j < 4; ++j)
        acc[i][j] = __builtin_amdgcn_mfma_f32_16x16x32_bf16(af[i], bfr[j], acc[i][j], 0, 0, 0);
  };

  // ---- prologue: stage tile 0
  loadA(0);
  stageB(Bs0, 0);
  writeA(As0);
  __syncthreads();

  // ---- main K-loop (R7 structure: one barrier per step, dbuf)
#pragma unroll
  for (int s = 0; s < NSTEP; ++s) {
    short* asC = (s & 1) ? As1 : As0;
    short* bsC = (s & 1) ? Bs1 : Bs0;
    short* asN = (s & 1) ? As0 : As1;
    short* bsN = (s & 1) ? Bs0 : Bs1;
    if (s + 1 < NSTEP) {
      loadA((s + 1) * BK);
      stageB(bsN, (s + 1) * BK);
    }
    compute(asC, bsC);
    if (s + 1 < NSTEP) {
      writeA(asN);
      __syncthreads();
    }
  }

  // ================================================================ conv phase
  __syncthreads();                 // all K-loop LDS reads complete

  // per-thread softmax weights for its channel
  const int cn  = t & 127;         // channel within panel
  const int dup = t >> 7;          // 0/1 -> run parity
  const int hh  = (n0 + cn) >> 6;  // head
  float wf[K_CONV];
  {
    float mx = -1e30f;
#pragma unroll
    for (int k = 0; k < K_CONV; ++k) { wf[k] = Wc[hh * K_CONV + k]; mx = fmaxf(mx, wf[k]); }
    float ssum = 0.f;
#pragma unroll
    for (int k = 0; k < K_CONV; ++k) { wf[k] = __expf(wf[k] - mx); ssum += wf[k]; }
    const float inv = 1.f / ssum;
#pragma unroll
    for (int k = 0; k < K_CONV; ++k) wf[k] *= inv;
  }

  // write transposed Y-tile: row = channel (0..127, 256B pitch), col = t
  // (bf16), byte ^= (ch&7)<<4. Lane's 4 acc regs = 4 consecutive t -> one
  // 8B ds_write. Invalid-t cols masked to ZERO (conv zero-padding; no bias).
  char* yt = (char*)LdsU;
  const bool edge = (chunk == 0) | (chunk == NCH - 1);
#pragma unroll
  for (int j = 0; j < 4; ++j) {
    const int nrow = wn + j * 16 + fr;
#pragma unroll
    for (int i = 0; i < 4; ++i) {
      const int tcol = wm + i * 16 + fq * 4;
      float e0 = acc[i][j][0] + bv[j];
      float e1 = acc[i][j][1] + bv[j];
      float e2 = acc[i][j][2] + bv[j];
      float e3 = acc[i][j][3] + bv[j];
      if (edge) {
        const int tb = tstart + tcol;
        e0 = ((unsigned)(tb + 0) < (unsigned)T_DIM) ? e0 : 0.f;
        e1 = ((unsigned)(tb + 1) < (unsigned)T_DIM) ? e1 : 0.f;
        e2 = ((unsigned)(tb + 2) < (unsigned)T_DIM) ? e2 : 0.f;
        e3 = ((unsigned)(tb + 3) < (unsigned)T_DIM) ? e3 : 0.f;
      }
      u32x2 pw;
      pw[0] = pack2(e0, e1);
      pw[1] = pack2(e2, e3);
      int byo = nrow * 256 + tcol * 2;
      byo ^= (nrow & 7) << 4;
      *(u32x2*)(yt + byo) = pw;
    }
  }
  __syncthreads();

  // conv + store: thread owns channel cn, runs {dup, dup+2, ..., dup+14}.
  // Window for run r: t in [r*8, r*8+16) = two aligned 16B chunks; outputs
  // local t = r*8+jj (+3 halo offset). run==15's w1 is never consumed by a
  // valid output (lidx<122 -> jj<=1 -> window stays inside w0).
  const long obase = (long)b * C_DIM + n0 + cn;
  const int swz = (cn & 7) << 4;
#pragma unroll
  for (int p = 0; p < 8; ++p) {
    const int run = dup + 2 * p;                 // 0..15
    const int rb  = cn * 256 + run * 16;
    u32x4 w0 = *(const u32x4*)(yt + (rb ^ swz));
    u32x4 w1 = (run < 15) ? *(const u32x4*)(yt + ((rb + 16) ^ swz)) : w0;
    f32x8 ya = unpack8(w0);
    f32x8 yb = unpack8(w1);
    float yw[16];
#pragma unroll
    for (int q = 0; q < 8; ++q) { yw[q] = ya[q]; yw[8 + q] = yb[q]; }
#pragma unroll
    for (int jj = 0; jj < 8; ++jj) {
      const int lidx = run * 8 + jj;             // output index in chunk
      const int tg   = chunk * TOUT + lidx;      // global t
      if (lidx < TOUT && tg < T_DIM) {
        float a = yw[jj] * wf[0];
#pragma unroll
        for (int k = 1; k < K_CONV; ++k) a += yw[jj + k] * wf[k];
        Out[(long)tg * BC + obase] = a;
      }
    }
  }
}

// ---------------------------------------------------------------- launch
extern "C" void kernel_launch(void* const* d_in, const int* in_sizes, int n_in,
                              void* d_out, int out_size, void* d_ws, size_t ws_size,
                              hipStream_t stream) {
  const float* x       = (const float*)d_in[0];  // (T,B,C) fp32
  const float* shift_W = (const float*)d_in[1];  // (C,C) fp32
  const float* shift_b = (const float*)d_in[2];  // (C) fp32
  const float* weight  = (const float*)d_in[3];  // (8,7) fp32
  float* out = (float*)d_out;

  unsigned short* Wq = (unsigned short*)d_ws;    // 512 KB bf16 Wq

  quantize_w<<<(C_DIM * C_DIM) / 256, 256, 0, stream>>>(shift_W, Wq);
  gemm_conv<<<NCH * B_DIM * (C_DIM / 128), 256, 0, stream>>>(
      x, (const short*)Wq, shift_b, weight, out);
}